// Round 1
// baseline (404.214 us; speedup 1.0000x reference)
//
#include <hip/hip_runtime.h>

// EMASlopeFilter: x (64,4096,64) fp32 -> (ema, slope, above, below, between), each (64,4096,64) fp32.
// Sequential EMA recurrence along T per (b,f) series; chunked with zero-carry warmup
// (omega^256 ~ 1.3e-9 => warmup error negligible; chunks 0/1/2 start at t=0 and are exact,
// which covers the entire early transient where |ema| reaches ~8e5 and the +-15 signal
// crossings at t~224; worst zero-carry truncation (chunk 3, warmup from t=128,
// |c_true|~5e3) is ~6e-6 absolute).
//
// Round 1: kNC 16->32 (kC 256->128). Rationale: kernel was ~185us of the 400us graph
// (other ~215us is the harness 1.34GB poison-fill, already at 78% HBM peak) but its own
// roofline is ~74-85us; rocprof showed only 4 waves/CU (1 block/CU, 12.5% occupancy),
// too few waves to hide the dependent-chain gaps between store bursts (achieved ~2.5TB/s).
// 512 blocks -> 2 blocks/CU = 8 waves/CU, and per-thread serial work 512->384 steps.
// Extra warmup re-reads are LLC-resident (input 67MB << 256MB Infinity Cache).

constexpr int kB  = 64;
constexpr int kT  = 4096;
constexpr int kF  = 64;
constexpr int kNC = 32;          // chunks along T
constexpr int kC  = kT / kNC;    // 128 output steps per chunk
constexpr int kW  = 256;         // warmup steps (zero-carry start)
constexpr int kLag = 25;
constexpr float kUpper = 15.0f;
constexpr float kLower = -15.0f;
constexpr size_t kN = (size_t)kB * kT * kF;   // 16777216 elements per output tensor

__global__ __launch_bounds__(256)
void ema_slope_kernel(const float* __restrict__ x, float* __restrict__ out) {
    const float kAlpha = (float)(2.0 / 26.0);
    const float kOm    = 1.0f - kAlpha;

    __shared__ float s_w[256];            // adjust weights, t in [0,256); w==1.0f beyond
    __shared__ float s_ring[256 * kLag];  // per-thread 25-deep ema ring (stride 25: 2-way banks, free)

    // Build w table: s_w[t] = max(1 - om^(t+1), 1e-10). Double accumulation ~= correctly
    // rounded f32 (matches host powf to <=1 ulp in practice).
    {
        const int t = threadIdx.x;
        const double omd = (double)kOm;
        double p = 1.0;
        for (int i = 0; i <= t; ++i) p *= omd;   // om^(t+1)
        s_w[t] = fmaxf(1.0f - (float)p, 1e-10f);
    }
    __syncthreads();

    const int lane  = threadIdx.x & 63;        // f
    const int wv    = threadIdx.x >> 6;        // wave in block
    const int chunk = blockIdx.x % kNC;        // all waves of a block share chunk
    const int b     = (blockIdx.x / kNC) * 4 + wv;

    const int t_out0 = chunk * kC;             // first output t
    const int t_end  = t_out0 + kC;            // exclusive
    const int tl0    = t_end - (kC + kW);      // 384-iteration window start (may be <0 for chunks 0-2)

    const float* xb = x   + (size_t)b * kT * kF + lane;
    float*       o0 = out + (size_t)b * kT * kF + lane;   // ema; others at +kN..+4kN

    float* ring = &s_ring[(size_t)threadIdx.x * kLag];

    float c;
    if (tl0 <= 0) {
        // chunks 0..2 start the recurrence exactly at t=0: ema0 = x0 (no adjust)
        c = xb[0];
        ring[0] = c;
        if (chunk == 0) {
            float slope = c;                       // lagged = 0 for t < 25
            o0[0]      = c;
            o0[kN]     = slope;
            o0[2 * kN] = (slope > kUpper) ? 1.0f : 0.0f;
            o0[3 * kN] = (slope < kLower) ? 1.0f : 0.0f;
            o0[4 * kN] = (slope >= kLower && slope <= kUpper) ? 1.0f : 0.0f;
        }
    } else {
        c = 0.0f;  // zero-carry warmup start; error ~ |c_true| * om^256 <= ~6e-6 abs
    }

    constexpr int G = 16;                       // load-pipeline depth (static register buffer)
    float xpre[G];
#pragma unroll
    for (int j = 0; j < G; ++j) {
        int tj = tl0 + j;
        float v = 0.0f;
        if (tj >= 0) v = xb[(size_t)tj * kF];
        xpre[j] = v;
    }

    const int ngroups = (kC + kW) / G;          // 24
    for (int g = 0; g < ngroups; ++g) {
        const int tg = tl0 + g * G;
        float xnext[G];
        if (g + 1 < ngroups) {
#pragma unroll
            for (int j = 0; j < G; ++j) {
                int tj = tg + G + j;
                float v = 0.0f;
                if (tj >= 0) v = xb[(size_t)tj * kF];
                xnext[j] = v;
            }
        }
#pragma unroll
        for (int j = 0; j < G; ++j) {
            const int tj = tg + j;
            if (tj >= 1) {
                // Mirror reference fp32 op order exactly (no FMA contraction):
                // e = alpha*x + om*c; c = e / max(1-om^(t+1),1e-10)  [w==1.0f for t>=256]
                float e = __fadd_rn(__fmul_rn(kAlpha, xpre[j]), __fmul_rn(kOm, c));
                c = (tj < 256) ? __fdiv_rn(e, s_w[tj]) : e;

                const int slot = (unsigned)tj % (unsigned)kLag;
                float lagv = ring[slot];        // ema[t-25] (written 25 steps ago)
                ring[slot] = c;

                if (tj >= t_out0) {
                    float slope = (tj >= kLag) ? __fsub_rn(c, lagv) : c;
                    size_t off = (size_t)tj * kF;
                    o0[off]          = c;
                    o0[off + kN]     = slope;
                    o0[off + 2 * kN] = (slope > kUpper) ? 1.0f : 0.0f;
                    o0[off + 3 * kN] = (slope < kLower) ? 1.0f : 0.0f;
                    o0[off + 4 * kN] = (slope >= kLower && slope <= kUpper) ? 1.0f : 0.0f;
                }
            }
        }
        if (g + 1 < ngroups) {
#pragma unroll
            for (int j = 0; j < G; ++j) xpre[j] = xnext[j];
        }
    }
}

extern "C" void kernel_launch(void* const* d_in, const int* in_sizes, int n_in,
                              void* d_out, int out_size, void* d_ws, size_t ws_size,
                              hipStream_t stream) {
    const float* x = (const float*)d_in[0];
    float* out = (float*)d_out;
    // 512 blocks x 256 threads: block = 4 waves (4 b-values) sharing one chunk;
    // 64 b x 32 chunks = 2048 waves total (8 waves/CU, 2 blocks/CU).
    dim3 grid(kB / 4 * kNC);
    dim3 block(256);
    ema_slope_kernel<<<grid, block, 0, stream>>>(x, out);
}

// Round 2
// 401.774 us; speedup vs baseline: 1.0061x; 1.0061x over previous
//
#include <hip/hip_runtime.h>

// EMASlopeFilter: x (64,4096,64) fp32 -> (ema, slope, above, below, between), each (64,4096,64) fp32.
// Sequential EMA recurrence along T per (b,f) series; chunked with zero-carry warmup
// (omega^256 ~ 1.3e-9 => warmup error negligible; chunks 0/1/2 start at t=0 and are exact,
// covering the early transient where |ema| ~ 8e5 and the +-15 signal crossings at t~224).
//
// Round 2: transposed burst writeback. Rounds 0/1 showed the kernel pinned at ~2.5 TB/s
// effective (neutral when occupancy doubled) while the harness fill hits 6.2 TB/s ->
// store-granularity/locality bound: 5 scalar dword stores/step = 10k concurrent 256B
// write streams. Now: ema recurrence writes into a per-wave LDS window (wave-private,
// no barriers); every 16 steps a transposed writeback emits 20x global_store_dwordx4
// (1KB/instr, 4KB contiguous per tensor per burst). Slope is computed at writeback from
// window row t-25, deleting the per-step ring/slope/signal/5-store tail entirely.

constexpr int kB  = 64;
constexpr int kT  = 4096;
constexpr int kF  = 64;
constexpr int kNC = 32;          // chunks along T
constexpr int kC  = kT / kNC;    // 128 output steps per chunk
constexpr int kW  = 256;         // warmup steps (zero-carry start)
constexpr int kLag = 25;
constexpr int kWin = 64;         // per-wave LDS ema window rows (pow2, > kTile + kLag)
constexpr float kUpper = 15.0f;
constexpr float kLower = -15.0f;
constexpr size_t kN = (size_t)kB * kT * kF;   // 16777216 elements per output tensor

__global__ __launch_bounds__(256)
void ema_slope_kernel(const float* __restrict__ x, float* __restrict__ out) {
    const float kAlpha = (float)(2.0 / 26.0);
    const float kOm    = 1.0f - kAlpha;

    __shared__ float s_w[256];                 // adjust weights, t in [0,256); w==1.0f beyond
    __shared__ float s_win[4][kWin][kF];       // per-wave ema window: 4 waves x 64 rows x 64 f (64 KB)

    // Build w table: s_w[t] = max(1 - om^(t+1), 1e-10). Double accumulation ~= correctly
    // rounded f32 (matches host powf to <=1 ulp in practice).
    {
        const int t = threadIdx.x;
        const double omd = (double)kOm;
        double p = 1.0;
        for (int i = 0; i <= t; ++i) p *= omd;   // om^(t+1)
        s_w[t] = fmaxf(1.0f - (float)p, 1e-10f);
    }
    __syncthreads();

    const int lane  = threadIdx.x & 63;        // f (recurrence phase)
    const int wv    = threadIdx.x >> 6;        // wave in block
    const int chunk = blockIdx.x % kNC;        // all waves of a block share chunk
    const int b     = (blockIdx.x / kNC) * 4 + wv;

    const int t_out0 = chunk * kC;             // first output t
    const int t_end  = t_out0 + kC;            // exclusive
    const int tl0    = t_end - (kC + kW);      // 384-iteration window start (<=0 for chunks 0-2)

    const float* xb = x   + (size_t)b * kT * kF + lane;
    float*       o0 = out + (size_t)b * kT * kF;          // ema; others at +kN..+4kN

    float (*win)[kF] = s_win[wv];              // wave-private: no __syncthreads needed

    float c;
    if (tl0 <= 0) {
        // chunks 0..2 start the recurrence exactly at t=0: ema0 = x0 (no adjust)
        c = xb[0];
        win[0][lane] = c;
    } else {
        c = 0.0f;  // zero-carry warmup start; error ~ |c_true| * om^256 (negligible, verified)
    }

    constexpr int G = 16;                       // group size = load-pipeline depth = writeback tile
    float xpre[G];
#pragma unroll
    for (int j = 0; j < G; ++j) {
        int tj = tl0 + j;
        xpre[j] = (tj >= 0) ? xb[(size_t)tj * kF] : 0.0f;
    }

    // writeback lane decomposition: lane l covers row (l>>4) of each 4-row quad, floats 4*(l&15)..+3
    const int rsub = lane >> 4;
    const int colf = (lane & 15) * 4;

    const int ngroups = (kC + kW) / G;          // 24
    for (int g = 0; g < ngroups; ++g) {
        const int tg = tl0 + g * G;
        float xnext[G];
        if (g + 1 < ngroups) {
#pragma unroll
            for (int j = 0; j < G; ++j) {
                int tj = tg + G + j;
                xnext[j] = (tj >= 0) ? xb[(size_t)tj * kF] : 0.0f;
            }
        }

        // window writes only needed for rows >= t_out0 - kLag (uniform hoistable predicate)
        const bool needw = (tg + G) > (t_out0 - kLag);

#pragma unroll
        for (int j = 0; j < G; ++j) {
            const int tj = tg + j;
            if (tj >= 1) {
                // Mirror reference fp32 op order exactly (no FMA contraction):
                // e = alpha*x + om*c; c = e / max(1-om^(t+1),1e-10)  [w==1.0f for t>=256]
                float e = __fadd_rn(__fmul_rn(kAlpha, xpre[j]), __fmul_rn(kOm, c));
                if (tj < 256) e = __fdiv_rn(e, s_w[tj]);   // wave-uniform branch (chunks 0-3 only)
                c = e;
                if (needw) win[tj & (kWin - 1)][lane] = c;
            }
        }

        // transposed burst writeback: this group's 16 rows are all in [t_out0, t_end)
        if (tg >= t_out0) {
#pragma unroll
            for (int r4 = 0; r4 < 4; ++r4) {
                const int row = tg + r4 * 4 + rsub;                    // absolute t (per-lane)
                const float4 ema4 = *(const float4*)&win[row & (kWin - 1)][colf];
                const float4 lraw = *(const float4*)&win[(row - kLag) & (kWin - 1)][colf];

                float4 sl;
                sl.x = (row >= kLag) ? __fsub_rn(ema4.x, lraw.x) : ema4.x;
                sl.y = (row >= kLag) ? __fsub_rn(ema4.y, lraw.y) : ema4.y;
                sl.z = (row >= kLag) ? __fsub_rn(ema4.z, lraw.z) : ema4.z;
                sl.w = (row >= kLag) ? __fsub_rn(ema4.w, lraw.w) : ema4.w;

                float4 sa, sb, sc;
                sa.x = (sl.x > kUpper) ? 1.0f : 0.0f;
                sa.y = (sl.y > kUpper) ? 1.0f : 0.0f;
                sa.z = (sl.z > kUpper) ? 1.0f : 0.0f;
                sa.w = (sl.w > kUpper) ? 1.0f : 0.0f;
                sb.x = (sl.x < kLower) ? 1.0f : 0.0f;
                sb.y = (sl.y < kLower) ? 1.0f : 0.0f;
                sb.z = (sl.z < kLower) ? 1.0f : 0.0f;
                sb.w = (sl.w < kLower) ? 1.0f : 0.0f;
                sc.x = (sl.x >= kLower && sl.x <= kUpper) ? 1.0f : 0.0f;
                sc.y = (sl.y >= kLower && sl.y <= kUpper) ? 1.0f : 0.0f;
                sc.z = (sl.z >= kLower && sl.z <= kUpper) ? 1.0f : 0.0f;
                sc.w = (sl.w >= kLower && sl.w <= kUpper) ? 1.0f : 0.0f;

                float* p = o0 + (size_t)(tg + r4 * 4) * kF + lane * 4;
                *(float4*)(p)          = ema4;
                *(float4*)(p + kN)     = sl;
                *(float4*)(p + 2 * kN) = sa;
                *(float4*)(p + 3 * kN) = sb;
                *(float4*)(p + 4 * kN) = sc;
            }
        }

        if (g + 1 < ngroups) {
#pragma unroll
            for (int j = 0; j < G; ++j) xpre[j] = xnext[j];
        }
    }
}

extern "C" void kernel_launch(void* const* d_in, const int* in_sizes, int n_in,
                              void* d_out, int out_size, void* d_ws, size_t ws_size,
                              hipStream_t stream) {
    const float* x = (const float*)d_in[0];
    float* out = (float*)d_out;
    // 512 blocks x 256 threads: block = 4 waves (4 b-values) sharing one chunk;
    // 64 b x 32 chunks = 2048 waves total (8 waves/CU, 2 blocks/CU; 65 KB LDS/block).
    dim3 grid(kB / 4 * kNC);
    dim3 block(256);
    ema_slope_kernel<<<grid, block, 0, stream>>>(x, out);
}

// Round 4
// 400.718 us; speedup vs baseline: 1.0087x; 1.0026x over previous
//
#include <hip/hip_runtime.h>

// EMASlopeFilter: x (64,4096,64) fp32 -> (ema, slope, above, below, between), each (64,4096,64) fp32.
// Sequential EMA recurrence along T per (b,f) series; chunked with zero-carry warmup
// (omega^256 ~ 1.3e-9 => warmup error negligible; chunks 0/1/2 start at t=0 and are exact,
// covering the early transient where |ema| ~ 8e5 and the +-15 signal crossings at t~224).
//
// Round 4: NONTEMPORAL output stores, type-fixed (clang ext_vector_type instead of HIP
// float4 -- __builtin_nontemporal_store requires a scalar/clang-vector pointee).
// Evidence: three structurally different kernels (scalar stores / 2x occupancy / 4KB
// burst stores) all land at 400-404us total => kernel (~185us) invariant to issue-side
// structure. Theory: output write path inflates HBM traffic (store-miss allocation
// and/or 335MB output stream evicting the 67MB input from LLC between warmup re-reads).
// The harness fill writes 1.34GB at 6.2TB/s with FETCH_SIZE~0; mimic with nt stores.
// Outputs are written once and never re-read => nt is semantically free.

constexpr int kB  = 64;
constexpr int kT  = 4096;
constexpr int kF  = 64;
constexpr int kNC = 32;          // chunks along T
constexpr int kC  = kT / kNC;    // 128 output steps per chunk
constexpr int kW  = 256;         // warmup steps (zero-carry start)
constexpr int kLag = 25;
constexpr int kWin = 64;         // per-wave LDS ema window rows (pow2, > tile + kLag)
constexpr float kUpper = 15.0f;
constexpr float kLower = -15.0f;
constexpr size_t kN = (size_t)kB * kT * kF;   // 16777216 elements per output tensor

typedef float vf4 __attribute__((ext_vector_type(4)));   // clang vector: nt-store compatible

__global__ __launch_bounds__(256)
void ema_slope_kernel(const float* __restrict__ x, float* __restrict__ out) {
    const float kAlpha = (float)(2.0 / 26.0);
    const float kOm    = 1.0f - kAlpha;

    __shared__ float s_w[256];                 // adjust weights, t in [0,256); w==1.0f beyond
    __shared__ float s_win[4][kWin][kF];       // per-wave ema window: 4 waves x 64 rows x 64 f (64 KB)

    // Build w table: s_w[t] = max(1 - om^(t+1), 1e-10). Double accumulation ~= correctly
    // rounded f32 (matches host powf to <=1 ulp in practice).
    {
        const int t = threadIdx.x;
        const double omd = (double)kOm;
        double p = 1.0;
        for (int i = 0; i <= t; ++i) p *= omd;   // om^(t+1)
        s_w[t] = fmaxf(1.0f - (float)p, 1e-10f);
    }
    __syncthreads();

    const int lane  = threadIdx.x & 63;        // f (recurrence phase)
    const int wv    = threadIdx.x >> 6;        // wave in block
    const int chunk = blockIdx.x % kNC;        // all waves of a block share chunk
    const int b     = (blockIdx.x / kNC) * 4 + wv;

    const int t_out0 = chunk * kC;             // first output t
    const int t_end  = t_out0 + kC;            // exclusive
    const int tl0    = t_end - (kC + kW);      // 384-iteration window start (<=0 for chunks 0-2)

    const float* xb = x   + (size_t)b * kT * kF + lane;
    float*       o0 = out + (size_t)b * kT * kF;          // ema; others at +kN..+4kN

    float (*win)[kF] = s_win[wv];              // wave-private: no __syncthreads needed

    float c;
    if (tl0 <= 0) {
        // chunks 0..2 start the recurrence exactly at t=0: ema0 = x0 (no adjust)
        c = xb[0];
        win[0][lane] = c;
    } else {
        c = 0.0f;  // zero-carry warmup start; error ~ |c_true| * om^256 (negligible, verified)
    }

    constexpr int G = 16;                       // group size = load-pipeline depth = writeback tile
    float xpre[G];
#pragma unroll
    for (int j = 0; j < G; ++j) {
        int tj = tl0 + j;
        xpre[j] = (tj >= 0) ? xb[(size_t)tj * kF] : 0.0f;
    }

    // writeback lane decomposition: lane l covers row (l>>4) of each 4-row quad, floats 4*(l&15)..+3
    const int rsub = lane >> 4;
    const int colf = (lane & 15) * 4;

    const int ngroups = (kC + kW) / G;          // 24
    for (int g = 0; g < ngroups; ++g) {
        const int tg = tl0 + g * G;
        float xnext[G];
        if (g + 1 < ngroups) {
#pragma unroll
            for (int j = 0; j < G; ++j) {
                int tj = tg + G + j;
                xnext[j] = (tj >= 0) ? xb[(size_t)tj * kF] : 0.0f;
            }
        }

        // window writes only needed for rows >= t_out0 - kLag (uniform hoistable predicate)
        const bool needw = (tg + G) > (t_out0 - kLag);

#pragma unroll
        for (int j = 0; j < G; ++j) {
            const int tj = tg + j;
            if (tj >= 1) {
                // Mirror reference fp32 op order exactly (no FMA contraction):
                // e = alpha*x + om*c; c = e / max(1-om^(t+1),1e-10)  [w==1.0f for t>=256]
                float e = __fadd_rn(__fmul_rn(kAlpha, xpre[j]), __fmul_rn(kOm, c));
                if (tj < 256) e = __fdiv_rn(e, s_w[tj]);   // wave-uniform branch (chunks 0-3 only)
                c = e;
                if (needw) win[tj & (kWin - 1)][lane] = c;
            }
        }

        // transposed burst writeback: this group's 16 rows are all in [t_out0, t_end)
        if (tg >= t_out0) {
#pragma unroll
            for (int r4 = 0; r4 < 4; ++r4) {
                const int row = tg + r4 * 4 + rsub;                    // absolute t (per-lane)
                const vf4 ema4 = *(const vf4*)&win[row & (kWin - 1)][colf];
                const vf4 lraw = *(const vf4*)&win[(row - kLag) & (kWin - 1)][colf];

                vf4 sl;
                sl.x = (row >= kLag) ? __fsub_rn(ema4.x, lraw.x) : ema4.x;
                sl.y = (row >= kLag) ? __fsub_rn(ema4.y, lraw.y) : ema4.y;
                sl.z = (row >= kLag) ? __fsub_rn(ema4.z, lraw.z) : ema4.z;
                sl.w = (row >= kLag) ? __fsub_rn(ema4.w, lraw.w) : ema4.w;

                vf4 sa, sb, sc;
                sa.x = (sl.x > kUpper) ? 1.0f : 0.0f;
                sa.y = (sl.y > kUpper) ? 1.0f : 0.0f;
                sa.z = (sl.z > kUpper) ? 1.0f : 0.0f;
                sa.w = (sl.w > kUpper) ? 1.0f : 0.0f;
                sb.x = (sl.x < kLower) ? 1.0f : 0.0f;
                sb.y = (sl.y < kLower) ? 1.0f : 0.0f;
                sb.z = (sl.z < kLower) ? 1.0f : 0.0f;
                sb.w = (sl.w < kLower) ? 1.0f : 0.0f;
                sc.x = (sl.x >= kLower && sl.x <= kUpper) ? 1.0f : 0.0f;
                sc.y = (sl.y >= kLower && sl.y <= kUpper) ? 1.0f : 0.0f;
                sc.z = (sl.z >= kLower && sl.z <= kUpper) ? 1.0f : 0.0f;
                sc.w = (sl.w >= kLower && sl.w <= kUpper) ? 1.0f : 0.0f;

                float* p = o0 + (size_t)(tg + r4 * 4) * kF + lane * 4;
                __builtin_nontemporal_store(ema4, (vf4*)(p));
                __builtin_nontemporal_store(sl,   (vf4*)(p + kN));
                __builtin_nontemporal_store(sa,   (vf4*)(p + 2 * kN));
                __builtin_nontemporal_store(sb,   (vf4*)(p + 3 * kN));
                __builtin_nontemporal_store(sc,   (vf4*)(p + 4 * kN));
            }
        }

        if (g + 1 < ngroups) {
#pragma unroll
            for (int j = 0; j < G; ++j) xpre[j] = xnext[j];
        }
    }
}

extern "C" void kernel_launch(void* const* d_in, const int* in_sizes, int n_in,
                              void* d_out, int out_size, void* d_ws, size_t ws_size,
                              hipStream_t stream) {
    const float* x = (const float*)d_in[0];
    float* out = (float*)d_out;
    // 512 blocks x 256 threads: block = 4 waves (4 b-values) sharing one chunk;
    // 64 b x 32 chunks = 2048 waves total (8 waves/CU, 2 blocks/CU; 65 KB LDS/block).
    dim3 grid(kB / 4 * kNC);
    dim3 block(256);
    ema_slope_kernel<<<grid, block, 0, stream>>>(x, out);
}